// Round 6
// baseline (170.243 us; speedup 1.0000x reference)
//
#include <hip/hip_runtime.h>
#include <math.h>

typedef float f32x2 __attribute__((ext_vector_type(2)));

constexpr int B = 32, D = 32, T = 16384, N = 128;
constexpr float MARG = 2e-5f;   // rel. 4/5-gap margin; ~3.8x worst-case bound

// numpy pairwise_sum (n=32): 8 accumulators + ordered combine, squares
// separately rounded. Bit-exact vs np.linalg.norm sumsq (validated R2).
__device__ __forceinline__ float np_pairwise32_sq(const float* v) {
#pragma clang fp contract(off)
    float r[8];
    #pragma unroll
    for (int j = 0; j < 8; ++j) r[j] = v[j] * v[j];
    #pragma unroll
    for (int i = 8; i < 32; i += 8) {
        #pragma unroll
        for (int j = 0; j < 8; ++j) r[j] += v[i + j] * v[i + j];
    }
    return ((r[0] + r[1]) + (r[2] + r[3])) + ((r[4] + r[5]) + (r[6] + r[7]));
}

// Same pairwise sum over f32x2-packed storage (element e -> v[e>>1], e&1).
__device__ __forceinline__ float np_pairwise32_sq2(const f32x2* v) {
#pragma clang fp contract(off)
    float r[8];
    #pragma unroll
    for (int j = 0; j < 8; ++j) {
        float x = (j & 1) ? v[j >> 1].y : v[j >> 1].x;
        r[j] = x * x;
    }
    #pragma unroll
    for (int i = 8; i < 32; i += 8) {
        #pragma unroll
        for (int j = 0; j < 8; ++j) {
            int e = i + j;
            float x = (e & 1) ? v[e >> 1].y : v[e >> 1].x;
            r[j] += x * x;
        }
    }
    return ((r[0] + r[1]) + (r[2] + r[3])) + ((r[4] + r[5]) + (r[6] + r[7]));
}

// Exact numpy einsum fold (validated bit-exact R2): sequential d ascending,
// mul and add separately rounded.
__device__ __forceinline__ float np_seq_dot(const float* __restrict__ sn,
                                            const float4* __restrict__ rw) {
#pragma clang fp contract(off)
    float acc = 0.0f;
    #pragma unroll
    for (int k = 0; k < 8; ++k) {
        float4 q = rw[k];
        acc += sn[4 * k + 0] * q.x;
        acc += sn[4 * k + 1] * q.y;
        acc += sn[4 * k + 2] * q.z;
        acc += sn[4 * k + 3] * q.w;
    }
    return acc;
}

// Sorted top-4 insert: values via max/med3, indices via cndmask.
// Strict > keeps the earlier (lower) index on exact ties (= jax top_k).
// Validated (absmax 0) in R5.
#define INSERT_STEP(v, n)                                                    \
    {                                                                        \
        bool c0 = (v) > t0, c1 = (v) > t1, c2 = (v) > t2, c3 = (v) > t3;     \
        float nt0 = fmaxf(t0, (v));                                          \
        float nt1 = __builtin_amdgcn_fmed3f((v), t1, t0);                    \
        float nt2 = __builtin_amdgcn_fmed3f((v), t2, t1);                    \
        float nt3 = __builtin_amdgcn_fmed3f((v), t3, t2);                    \
        int ni0 = c0 ? (n) : i0;                                             \
        int ni1 = c1 ? (c0 ? i0 : (n)) : i1;                                 \
        int ni2 = c2 ? (c1 ? i1 : (n)) : i2;                                 \
        int ni3 = c3 ? (c2 ? i2 : (n)) : i3;                                 \
        t0 = nt0; t1 = nt1; t2 = nt2; t3 = nt3;                              \
        i0 = ni0; i1 = ni1; i2 = ni2; i3 = ni3;                              \
    }

__global__ __launch_bounds__(256) void ve_kernel(
    const float* __restrict__ source,   // [B][D][T]
    const float* __restrict__ tokens,   // [D][N]
    float* __restrict__ out)            // [B][D][T]
{
    __shared__ float rn[N][D];      // normalized refs: LDS broadcast operand
    __shared__ float rf[N][D + 4];  // raw refs; +4 pad keeps rows 16B-aligned

    for (int i = threadIdx.x; i < N * D; i += 256) {
        int d = i >> 7, n = i & (N - 1);
        rf[n][d] = tokens[i];
    }
    __syncthreads();

    if (threadIdx.x < N) {
        int n = threadIdx.x;
        float tq[D];
        #pragma unroll
        for (int d = 0; d < D; ++d) tq[d] = rf[n][d];
        float nrm = sqrtf(np_pairwise32_sq(tq));
        #pragma unroll
        for (int d = 0; d < D; ++d) rn[n][d] = tq[d] / nrm;
    }
    __syncthreads();

    int gid = blockIdx.x * 256 + threadIdx.x;
    int b = gid >> 14, t = gid & (T - 1);

    const float* src = source + (size_t)b * D * T + t;
    f32x2 s2[16];
    #pragma unroll
    for (int k = 0; k < 16; ++k) {
        s2[k].x = src[(size_t)(2 * k) * T];
        s2[k].y = src[(size_t)(2 * k + 1) * T];
    }
    float nrm = sqrtf(np_pairwise32_sq2(s2));   // np-exact query norm

    float t0 = -INFINITY, t1 = -INFINITY, t2 = -INFINITY, t3 = -INFINITY;
    float m5 = -INFINITY;
    int i0 = 0, i1 = 0, i2 = 0, i3 = 0;

    #pragma unroll 4
    for (int n = 0; n < N; ++n) {
        // LDS broadcast reads (uniform address): 8x ds_read_b128.
        const float4* rw = reinterpret_cast<const float4*>(&rn[n][0]);
        f32x2 a0 = {0.f, 0.f}, a1 = {0.f, 0.f};
        f32x2 a2 = {0.f, 0.f}, a3 = {0.f, 0.f};
        #pragma unroll
        for (int k = 0; k < 4; ++k) {
            float4 q0 = rw[2 * k], q1 = rw[2 * k + 1];
            f32x2 qa = {q0.x, q0.y}, qb = {q0.z, q0.w};
            f32x2 qc = {q1.x, q1.y}, qd = {q1.z, q1.w};
            a0 += s2[4 * k + 0] * qa;   // contract(fast) -> v_pk_fma_f32
            a1 += s2[4 * k + 1] * qb;
            a2 += s2[4 * k + 2] * qc;
            a3 += s2[4 * k + 3] * qd;
        }
        f32x2 h = (a0 + a2) + (a1 + a3);
        float v = h.x + h.y;                // approx raw dot (norm-free)

        m5 = fmaxf(m5, fminf(v, t3));       // running max of non-top-4
        INSERT_STEP(v, n);
    }

    // Ambiguous 4/5 boundary under rounding differences -> bit-exact re-walk
    // with the validated numpy-fold path.
    if (t3 - m5 <= MARG * nrm) {
        float sn[D];
        #pragma unroll
        for (int k = 0; k < 16; ++k) {
            sn[2 * k]     = s2[k].x / nrm;  // IEEE div, matches np
            sn[2 * k + 1] = s2[k].y / nrm;
        }
        t0 = t1 = t2 = t3 = -INFINITY;
        i0 = i1 = i2 = i3 = 0;
        for (int n = 0; n < N; ++n) {
            float v = np_seq_dot(sn, reinterpret_cast<const float4*>(&rn[n][0]));
            INSERT_STEP(v, n);
        }
    }

    // Gather + mean in top-k order (b128 reads; rows 16B-aligned).
    const float4* g0 = reinterpret_cast<const float4*>(&rf[i0][0]);
    const float4* g1 = reinterpret_cast<const float4*>(&rf[i1][0]);
    const float4* g2 = reinterpret_cast<const float4*>(&rf[i2][0]);
    const float4* g3 = reinterpret_cast<const float4*>(&rf[i3][0]);
    float* dst = out + (size_t)b * D * T + t;
    #pragma unroll
    for (int k = 0; k < 8; ++k) {
        float4 v0 = g0[k], v1 = g1[k], v2 = g2[k], v3 = g3[k];
        dst[(size_t)(4 * k + 0) * T] = (((v0.x + v1.x) + v2.x) + v3.x) * 0.25f;
        dst[(size_t)(4 * k + 1) * T] = (((v0.y + v1.y) + v2.y) + v3.y) * 0.25f;
        dst[(size_t)(4 * k + 2) * T] = (((v0.z + v1.z) + v2.z) + v3.z) * 0.25f;
        dst[(size_t)(4 * k + 3) * T] = (((v0.w + v1.w) + v2.w) + v3.w) * 0.25f;
    }
}

extern "C" void kernel_launch(void* const* d_in, const int* in_sizes, int n_in,
                              void* d_out, int out_size, void* d_ws, size_t ws_size,
                              hipStream_t stream) {
    const float* source = (const float*)d_in[0];
    const float* tokens = (const float*)d_in[1];
    float* out = (float*)d_out;

    dim3 grid((B * T) / 256), block(256);
    ve_kernel<<<grid, block, 0, stream>>>(source, tokens, out);
}

// Round 7
// 139.947 us; speedup vs baseline: 1.2165x; 1.2165x over previous
//
#include <hip/hip_runtime.h>
#include <math.h>

constexpr int B = 32, D = 32, T = 16384, N = 128;
constexpr int HALF_T = T / 2;

// numpy pairwise_sum (n=32): 8 accumulators + ordered combine, squares
// separately rounded. Bit-exact vs np.linalg.norm sumsq (validated R2).
__device__ __forceinline__ float np_pairwise32_sq(const float* v) {
#pragma clang fp contract(off)
    float r[8];
    #pragma unroll
    for (int j = 0; j < 8; ++j) r[j] = v[j] * v[j];
    #pragma unroll
    for (int i = 8; i < 32; i += 8) {
        #pragma unroll
        for (int j = 0; j < 8; ++j) r[j] += v[i + j] * v[i + j];
    }
    return ((r[0] + r[1]) + (r[2] + r[3])) + ((r[4] + r[5]) + (r[6] + r[7]));
}

// Branchless sorted top-4 insert (strict > : lower index wins ties).
// Exactly R2's validated form, parameterized by state suffix.
#define INSERT4(v, n, tv0, tv1, tv2, tv3, ti0, ti1, ti2, ti3)                \
    {                                                                        \
        bool c0 = (v) > tv0, c1 = (v) > tv1, c2 = (v) > tv2, c3 = (v) > tv3; \
        float nv3 = c3 ? (c2 ? tv2 : (v)) : tv3;  int ni3 = c3 ? (c2 ? ti2 : (n)) : ti3; \
        float nv2 = c2 ? (c1 ? tv1 : (v)) : tv2;  int ni2 = c2 ? (c1 ? ti1 : (n)) : ti2; \
        float nv1 = c1 ? (c0 ? tv0 : (v)) : tv1;  int ni1 = c1 ? (c0 ? ti0 : (n)) : ti1; \
        float nv0 = c0 ? (v) : tv0;               int ni0 = c0 ? (n) : ti0;  \
        tv0 = nv0; tv1 = nv1; tv2 = nv2; tv3 = nv3;                          \
        ti0 = ni0; ti1 = ni1; ti2 = ni2; ti3 = ni3;                          \
    }

__global__ __launch_bounds__(256) void ve_kernel(
    const float* __restrict__ source,   // [B][D][T]
    const float* __restrict__ tokens,   // [D][N]
    float* __restrict__ out)            // [B][D][T]
{
    __shared__ float rn[N][D];      // np-bit-exact normalized refs
    __shared__ float rf[N][D + 1];  // raw refs, +1 pad for the gather

    for (int i = threadIdx.x; i < N * D; i += 256) {
        int d = i >> 7, n = i & (N - 1);
        rf[n][d] = tokens[i];
    }
    __syncthreads();

    if (threadIdx.x < N) {
        int n = threadIdx.x;
        float tq[D];
        #pragma unroll
        for (int d = 0; d < D; ++d) tq[d] = rf[n][d];
        float nrm = sqrtf(np_pairwise32_sq(tq));
        #pragma unroll
        for (int d = 0; d < D; ++d) rn[n][d] = tq[d] / nrm;
    }
    __syncthreads();

    // Two queries per thread: (b, t) and (b, t + T/2); both runs coalesced.
    int gid = blockIdx.x * 256 + threadIdx.x;       // [0, B*T/2)
    int b = gid >> 13;                               // / (T/2)
    int t = gid & (HALF_T - 1);

    const float* src = source + (size_t)b * D * T + t;
    float sn0[D], sn1[D];
    {
        float s0[D], s1[D];
        #pragma unroll
        for (int d = 0; d < D; ++d) {
            s0[d] = src[(size_t)d * T];
            s1[d] = src[(size_t)d * T + HALF_T];
        }
        float n0 = sqrtf(np_pairwise32_sq(s0));
        float n1 = sqrtf(np_pairwise32_sq(s1));
        #pragma unroll
        for (int d = 0; d < D; ++d) { sn0[d] = s0[d] / n0; sn1[d] = s1[d] / n1; }
    }

    float av0 = -INFINITY, av1 = -INFINITY, av2 = -INFINITY, av3 = -INFINITY;
    int   ai0 = 0, ai1 = 0, ai2 = 0, ai3 = 0;
    float bv0 = -INFINITY, bv1 = -INFINITY, bv2 = -INFINITY, bv3 = -INFINITY;
    int   bi0 = 0, bi1 = 0, bi2 = 0, bi3 = 0;

    for (int n = 0; n < N; ++n) {
#pragma clang fp contract(off)
        // Exact numpy einsum fold for BOTH queries, sharing the rw[k] reads.
        // Sequential d ascending, mul and add separately rounded (R2-proven).
        const float4* rw = reinterpret_cast<const float4*>(&rn[n][0]);
        float a = 0.0f, c = 0.0f;
        #pragma unroll
        for (int k = 0; k < 8; ++k) {
            float4 q = rw[k];
            a += sn0[4 * k + 0] * q.x;
            a += sn0[4 * k + 1] * q.y;
            a += sn0[4 * k + 2] * q.z;
            a += sn0[4 * k + 3] * q.w;
            c += sn1[4 * k + 0] * q.x;
            c += sn1[4 * k + 1] * q.y;
            c += sn1[4 * k + 2] * q.z;
            c += sn1[4 * k + 3] * q.w;
        }
        INSERT4(a, n, av0, av1, av2, av3, ai0, ai1, ai2, ai3);
        INSERT4(c, n, bv0, bv1, bv2, bv3, bi0, bi1, bi2, bi3);
    }

    // Gather + mean in top-k order; /4 exact via *0.25 (R2-proven epilogue).
    float* dst = out + (size_t)b * D * T + t;
    #pragma unroll
    for (int d = 0; d < D; ++d) {
        float sa = ((rf[ai0][d] + rf[ai1][d]) + rf[ai2][d]) + rf[ai3][d];
        float sb = ((rf[bi0][d] + rf[bi1][d]) + rf[bi2][d]) + rf[bi3][d];
        dst[(size_t)d * T] = sa * 0.25f;
        dst[(size_t)d * T + HALF_T] = sb * 0.25f;
    }
}

extern "C" void kernel_launch(void* const* d_in, const int* in_sizes, int n_in,
                              void* d_out, int out_size, void* d_ws, size_t ws_size,
                              hipStream_t stream) {
    const float* source = (const float*)d_in[0];
    const float* tokens = (const float*)d_in[1];
    float* out = (float*)d_out;

    dim3 grid((B * T / 2) / 256), block(256);
    ve_kernel<<<grid, block, 0, stream>>>(source, tokens, out);
}